// Round 3
// baseline (290.354 us; speedup 1.0000x reference)
//
#include <hip/hip_runtime.h>

// UniformBottomUpHTMM: T=64 trees, depth 10 (N1=2047 heap layout), C=16,
// M=64, G=16. r14: kill the scratch spill. r13's counters showed Phase B
// writes ~90 KB/block of scratch (92 MB device-wide) EVEN at VGPR=128 --
// the (256,2) cap forced partial spill of the fully-unrolled leaf+L9+L8
// DAG (4x b[16] + 2x bp[16] + s8[16] + s9[16] live under ILP scheduling).
// Per-unit write traffic was identical in r11 (79 KB) -- the device
// barrier was never the write source; scratch was, all along.
// Fixes: (a) NO __launch_bounds__ -> allocator uses natural demand, zero
// spill (lesson r12: min-waves arg maps to ~256/w VGPR cap; any cap below
// demand = spill storm). (b) '#pragma unroll 1' on the c9/cl subtree loops
// so only one subtree's temporaries are live at a time, cutting natural
// demand toward <=128 (each rolled iter is a full 16x16 matvec; overhead
// noise). Structure unchanged: 1024 independent blocks, one (t,g) each,
// no workspace, no atomics, no device barrier.

#define C_DIM 16
#define M_DIM 64
#define G_DIM 16
#define T_TREES 64
#define N1 2047
#define NBLOCKS (T_TREES * G_DIM)   // 1024

__global__ void htmm_fused(
    const int* __restrict__ x,
    const int* __restrict__ inv_map,
    const float* __restrict__ lA,
    const float* __restrict__ lB,
    const float* __restrict__ lPi,
    float* __restrict__ out)
{
    const int bid = blockIdx.x;           // 1024 blocks: g = bid>>6, t = bid&63
    const int tid = threadIdx.x;
    const int g = bid >> 6;
    const int t = bid & (T_TREES - 1);    // all 16 same-tree blocks land on one XCD (64%8==0)

    __shared__ __align__(16) float sA[C_DIM * C_DIM];
    __shared__ __align__(16) float sB[C_DIM * M_DIM];
    __shared__ __align__(16) float sPi[C_DIM];
    __shared__ __align__(16) unsigned char xs[2048];
    __shared__ float buf0[C_DIM * 256];   // L8 betas (SoA stride 256)
    __shared__ float buf1[C_DIM * 128];
    __shared__ float wsum[4];

    // ---- per-block staging: tree symbols (coalesced; 16 blocks/tree hit L2) ----
    {
        const int base = t * N1;
        for (int i = tid; i < N1; i += 256)
            xs[i] = (unsigned char)x[inv_map[base + i]];
    }
    // ---- per-block param softmax for this g ----
    {   // A: softmax over i (axis 0) within 16-lane segments; one (i,j)/thread
        int j = tid >> 4, i = tid & 15;
        float v = lA[(i * C_DIM + j) * G_DIM + g];
        float mx = v;
        #pragma unroll
        for (int m = 1; m < 16; m <<= 1) mx = fmaxf(mx, __shfl_xor(mx, m, 16));
        float e = __expf(v - mx);
        float s = e;
        #pragma unroll
        for (int m = 1; m < 16; m <<= 1) s += __shfl_xor(s, m, 16);
        sA[i * C_DIM + j] = e / s;
    }
    {   // B: softmax over m (axis 1), row c, 4 symbols per lane
        int c = tid >> 4, l16 = tid & 15;
        float e0 = lB[(c * M_DIM + l16 +  0) * G_DIM + g];
        float e1 = lB[(c * M_DIM + l16 + 16) * G_DIM + g];
        float e2 = lB[(c * M_DIM + l16 + 32) * G_DIM + g];
        float e3 = lB[(c * M_DIM + l16 + 48) * G_DIM + g];
        float mx = fmaxf(fmaxf(e0, e1), fmaxf(e2, e3));
        #pragma unroll
        for (int m = 1; m < 16; m <<= 1) mx = fmaxf(mx, __shfl_xor(mx, m, 16));
        e0 = __expf(e0 - mx); e1 = __expf(e1 - mx);
        e2 = __expf(e2 - mx); e3 = __expf(e3 - mx);
        float s = e0 + e1 + e2 + e3;
        #pragma unroll
        for (int m = 1; m < 16; m <<= 1) s += __shfl_xor(s, m, 16);
        float inv = 1.f / s;
        sB[c * M_DIM + l16 +  0] = e0 * inv;
        sB[c * M_DIM + l16 + 16] = e1 * inv;
        sB[c * M_DIM + l16 + 32] = e2 * inv;
        sB[c * M_DIM + l16 + 48] = e3 * inv;
    }
    if (tid < C_DIM) {  // Pi: softmax over c across lanes 0..15
        float v = lPi[tid * G_DIM + g];
        float mx = v;
        #pragma unroll
        for (int m = 1; m < 16; m <<= 1) mx = fmaxf(mx, __shfl_xor(mx, m, 16));
        float e = __expf(v - mx);
        float s = e;
        #pragma unroll
        for (int m = 1; m < 16; m <<= 1) s += __shfl_xor(s, m, 16);
        sPi[tid] = e / s;
    }
    __syncthreads();

    float ll = 0.f;

    // ---- fused leaves (L10) + L9 + L8: one L8 node per thread ----
    // c9/cl loops kept ROLLED (unroll 1) to limit live temporaries.
    {
        const int idx = tid;
        const int p8  = 255 + idx;
        float s8[C_DIM];
        #pragma unroll
        for (int k = 0; k < C_DIM; ++k) s8[k] = 0.f;
        #pragma unroll 1
        for (int c9 = 0; c9 < 2; ++c9) {
            const int p9 = 2 * p8 + 1 + c9;
            float s9[C_DIM];
            #pragma unroll
            for (int k = 0; k < C_DIM; ++k) s9[k] = 0.f;
            #pragma unroll 1
            for (int cl = 0; cl < 2; ++cl) {
                const int xv = xs[2 * p9 + 1 + cl];
                float b[C_DIM]; float nu = 0.f;
                #pragma unroll
                for (int k = 0; k < C_DIM; ++k) {
                    b[k] = sPi[k] * sB[k * M_DIM + xv];
                    nu += b[k];
                }
                float inv = 0.5f / nu;
                #pragma unroll
                for (int k = 0; k < C_DIM; ++k) s9[k] += b[k] * inv;
                ll += __logf(nu);
            }
            const int xv = xs[p9];
            float bp[C_DIM]; float nu = 0.f;
            #pragma unroll
            for (int i = 0; i < C_DIM; ++i) {
                float ti = 0.f;
                #pragma unroll
                for (int j = 0; j < C_DIM; ++j) ti += sA[i * C_DIM + j] * s9[j];
                bp[i] = ti * sB[i * M_DIM + xv];
                nu += bp[i];
            }
            ll += __logf(nu);
            float inv = 0.5f / nu;
            #pragma unroll
            for (int k = 0; k < C_DIM; ++k) s8[k] += bp[k] * inv;
        }
        const int xv = xs[p8];
        float bp[C_DIM]; float nu = 0.f;
        #pragma unroll
        for (int i = 0; i < C_DIM; ++i) {
            float ti = 0.f;
            #pragma unroll
            for (int j = 0; j < C_DIM; ++j) ti += sA[i * C_DIM + j] * s8[j];
            bp[i] = ti * sB[i * M_DIM + xv];
            nu += bp[i];
        }
        ll += __logf(nu);
        float inv = 1.f / nu;
        #pragma unroll
        for (int k = 0; k < C_DIM; ++k) buf0[k * 256 + idx] = bp[k] * inv;
    }
    __syncthreads();

    // ---- L7: 128 nodes ----
    if (tid < 128) {
        const int idx = tid;
        float s[C_DIM];
        #pragma unroll
        for (int j = 0; j < C_DIM; ++j) {
            float2 cv = ((const float2*)(buf0 + j * 256))[idx];
            s[j] = 0.5f * (cv.x + cv.y);
        }
        const int xv = xs[127 + idx];
        float bp[C_DIM]; float nu = 0.f;
        #pragma unroll
        for (int i = 0; i < C_DIM; ++i) {
            float ti = 0.f;
            #pragma unroll
            for (int j = 0; j < C_DIM; ++j) ti += sA[i * C_DIM + j] * s[j];
            bp[i] = ti * sB[i * M_DIM + xv];
            nu += bp[i];
        }
        ll += __logf(nu);
        float inv = 1.f / nu;
        #pragma unroll
        for (int i = 0; i < C_DIM; ++i) buf1[i * 128 + idx] = bp[i] * inv;
    }
    __syncthreads();

    // ---- L6..L0 (64..1 nodes): wave 0 only, LDS fences not barriers ----
    if (tid < 64) {
        float* cur = buf1; int cs = 128;
        float* nxt = buf0; int ns = 256;
        for (int cnt2 = 64; cnt2 >= 1; cnt2 >>= 1) {
            if (tid < cnt2) {
                const int idx = tid;
                float s[C_DIM];
                #pragma unroll
                for (int j = 0; j < C_DIM; ++j) {
                    float a  = cur[j * cs + 2 * idx];
                    float b2 = cur[j * cs + 2 * idx + 1];
                    s[j] = 0.5f * (a + b2);
                }
                const int xv = xs[cnt2 - 1 + idx];
                float bp[C_DIM]; float nu = 0.f;
                #pragma unroll
                for (int i = 0; i < C_DIM; ++i) {
                    float ti = 0.f;
                    #pragma unroll
                    for (int j = 0; j < C_DIM; ++j) ti += sA[i * C_DIM + j] * s[j];
                    bp[i] = ti * sB[i * M_DIM + xv];
                    nu += bp[i];
                }
                ll += __logf(nu);
                float inv = 1.f / nu;
                #pragma unroll
                for (int i = 0; i < C_DIM; ++i) nxt[i * ns + idx] = bp[i] * inv;
            }
            asm volatile("s_waitcnt lgkmcnt(0)" ::: "memory");
            __builtin_amdgcn_wave_barrier();
            float* tp = cur; cur = nxt; nxt = tp;
            int ts = cs; cs = ns; ns = ts;
        }
    }

    // ---- reduce ll across block ----
    float v = ll;
    #pragma unroll
    for (int off = 32; off > 0; off >>= 1) v += __shfl_down(v, off, 64);
    if ((tid & 63) == 0) wsum[tid >> 6] = v;
    __syncthreads();
    if (tid == 0) out[t * G_DIM + g] = wsum[0] + wsum[1] + wsum[2] + wsum[3];
}

extern "C" void kernel_launch(void* const* d_in, const int* in_sizes, int n_in,
                              void* d_out, int out_size, void* d_ws, size_t ws_size,
                              hipStream_t stream) {
    const int*   x       = (const int*)d_in[0];
    const int*   inv_map = (const int*)d_in[6];
    const float* lA      = (const float*)d_in[7];
    const float* lB      = (const float*)d_in[8];
    const float* lPi     = (const float*)d_in[9];
    float* out = (float*)d_out;

    htmm_fused<<<dim3(NBLOCKS), dim3(256), 0, stream>>>(
        x, inv_map, lA, lB, lPi, out);
}

// Round 4
// 170.291 us; speedup vs baseline: 1.7050x; 1.7050x over previous
//
#include <hip/hip_runtime.h>

// UniformBottomUpHTMM: T=64 trees, depth 10 (N1=2047 heap layout), C=16,
// M=64, G=16. r15: the UNCONFOUNDED spill fix. History of the spill hunt:
//   r13: (256,2) cap=128, full unroll  -> 140 MB scratch traffic, 84 us
//   r14: no bounds     cap=64 (hipcc compiles for worst-case 1024-thread
//        blocks when no __launch_bounds__!), unroll 1 -> 548 MB, 226 us
// r14 changed two levers at once; the launch-bounds lever backfired
// (64-reg cap = tighter than r13) and masked the unroll lever. r15 keeps
// '#pragma unroll 1' on the c9/cl subtree loops (rolled live-set ~60-80
// VGPR: s8[16]+s9[16]+b[16]+bases) AND restores __launch_bounds__(256,2)
// (proven cap=128). Demand < cap -> zero spill is the prediction.
// Structure: 1024 independent blocks, one (t,g) each, no workspace, no
// atomics, no device barrier. Each block gathers its tree's 2047 symbols
// (L2-shared by 16 blocks) and recomputes its g's softmax params in LDS.

#define C_DIM 16
#define M_DIM 64
#define G_DIM 16
#define T_TREES 64
#define N1 2047
#define NBLOCKS (T_TREES * G_DIM)   // 1024

__global__ __launch_bounds__(256, 2) void htmm_fused(
    const int* __restrict__ x,
    const int* __restrict__ inv_map,
    const float* __restrict__ lA,
    const float* __restrict__ lB,
    const float* __restrict__ lPi,
    float* __restrict__ out)
{
    const int bid = blockIdx.x;           // 1024 blocks: g = bid>>6, t = bid&63
    const int tid = threadIdx.x;
    const int g = bid >> 6;
    const int t = bid & (T_TREES - 1);    // all 16 same-tree blocks land on one XCD (64%8==0)

    __shared__ __align__(16) float sA[C_DIM * C_DIM];
    __shared__ __align__(16) float sB[C_DIM * M_DIM];
    __shared__ __align__(16) float sPi[C_DIM];
    __shared__ __align__(16) unsigned char xs[2048];
    __shared__ float buf0[C_DIM * 256];   // L8 betas (SoA stride 256)
    __shared__ float buf1[C_DIM * 128];
    __shared__ float wsum[4];

    // ---- per-block staging: tree symbols (coalesced; 16 blocks/tree hit L2) ----
    {
        const int base = t * N1;
        for (int i = tid; i < N1; i += 256)
            xs[i] = (unsigned char)x[inv_map[base + i]];
    }
    // ---- per-block param softmax for this g ----
    {   // A: softmax over i (axis 0) within 16-lane segments; one (i,j)/thread
        int j = tid >> 4, i = tid & 15;
        float v = lA[(i * C_DIM + j) * G_DIM + g];
        float mx = v;
        #pragma unroll
        for (int m = 1; m < 16; m <<= 1) mx = fmaxf(mx, __shfl_xor(mx, m, 16));
        float e = __expf(v - mx);
        float s = e;
        #pragma unroll
        for (int m = 1; m < 16; m <<= 1) s += __shfl_xor(s, m, 16);
        sA[i * C_DIM + j] = e / s;
    }
    {   // B: softmax over m (axis 1), row c, 4 symbols per lane
        int c = tid >> 4, l16 = tid & 15;
        float e0 = lB[(c * M_DIM + l16 +  0) * G_DIM + g];
        float e1 = lB[(c * M_DIM + l16 + 16) * G_DIM + g];
        float e2 = lB[(c * M_DIM + l16 + 32) * G_DIM + g];
        float e3 = lB[(c * M_DIM + l16 + 48) * G_DIM + g];
        float mx = fmaxf(fmaxf(e0, e1), fmaxf(e2, e3));
        #pragma unroll
        for (int m = 1; m < 16; m <<= 1) mx = fmaxf(mx, __shfl_xor(mx, m, 16));
        e0 = __expf(e0 - mx); e1 = __expf(e1 - mx);
        e2 = __expf(e2 - mx); e3 = __expf(e3 - mx);
        float s = e0 + e1 + e2 + e3;
        #pragma unroll
        for (int m = 1; m < 16; m <<= 1) s += __shfl_xor(s, m, 16);
        float inv = 1.f / s;
        sB[c * M_DIM + l16 +  0] = e0 * inv;
        sB[c * M_DIM + l16 + 16] = e1 * inv;
        sB[c * M_DIM + l16 + 32] = e2 * inv;
        sB[c * M_DIM + l16 + 48] = e3 * inv;
    }
    if (tid < C_DIM) {  // Pi: softmax over c across lanes 0..15
        float v = lPi[tid * G_DIM + g];
        float mx = v;
        #pragma unroll
        for (int m = 1; m < 16; m <<= 1) mx = fmaxf(mx, __shfl_xor(mx, m, 16));
        float e = __expf(v - mx);
        float s = e;
        #pragma unroll
        for (int m = 1; m < 16; m <<= 1) s += __shfl_xor(s, m, 16);
        sPi[tid] = e / s;
    }
    __syncthreads();

    float ll = 0.f;

    // ---- fused leaves (L10) + L9 + L8: one L8 node per thread ----
    // c9/cl loops kept ROLLED (unroll 1) to bound live temporaries under
    // the 128-VGPR cap.
    {
        const int idx = tid;
        const int p8  = 255 + idx;
        float s8[C_DIM];
        #pragma unroll
        for (int k = 0; k < C_DIM; ++k) s8[k] = 0.f;
        #pragma unroll 1
        for (int c9 = 0; c9 < 2; ++c9) {
            const int p9 = 2 * p8 + 1 + c9;
            float s9[C_DIM];
            #pragma unroll
            for (int k = 0; k < C_DIM; ++k) s9[k] = 0.f;
            #pragma unroll 1
            for (int cl = 0; cl < 2; ++cl) {
                const int xv = xs[2 * p9 + 1 + cl];
                float b[C_DIM]; float nu = 0.f;
                #pragma unroll
                for (int k = 0; k < C_DIM; ++k) {
                    b[k] = sPi[k] * sB[k * M_DIM + xv];
                    nu += b[k];
                }
                float inv = 0.5f / nu;
                #pragma unroll
                for (int k = 0; k < C_DIM; ++k) s9[k] += b[k] * inv;
                ll += __logf(nu);
            }
            const int xv = xs[p9];
            float bp[C_DIM]; float nu = 0.f;
            #pragma unroll
            for (int i = 0; i < C_DIM; ++i) {
                float ti = 0.f;
                #pragma unroll
                for (int j = 0; j < C_DIM; ++j) ti += sA[i * C_DIM + j] * s9[j];
                bp[i] = ti * sB[i * M_DIM + xv];
                nu += bp[i];
            }
            ll += __logf(nu);
            float inv = 0.5f / nu;
            #pragma unroll
            for (int k = 0; k < C_DIM; ++k) s8[k] += bp[k] * inv;
        }
        const int xv = xs[p8];
        float bp[C_DIM]; float nu = 0.f;
        #pragma unroll
        for (int i = 0; i < C_DIM; ++i) {
            float ti = 0.f;
            #pragma unroll
            for (int j = 0; j < C_DIM; ++j) ti += sA[i * C_DIM + j] * s8[j];
            bp[i] = ti * sB[i * M_DIM + xv];
            nu += bp[i];
        }
        ll += __logf(nu);
        float inv = 1.f / nu;
        #pragma unroll
        for (int k = 0; k < C_DIM; ++k) buf0[k * 256 + idx] = bp[k] * inv;
    }
    __syncthreads();

    // ---- L7: 128 nodes ----
    if (tid < 128) {
        const int idx = tid;
        float s[C_DIM];
        #pragma unroll
        for (int j = 0; j < C_DIM; ++j) {
            float2 cv = ((const float2*)(buf0 + j * 256))[idx];
            s[j] = 0.5f * (cv.x + cv.y);
        }
        const int xv = xs[127 + idx];
        float bp[C_DIM]; float nu = 0.f;
        #pragma unroll
        for (int i = 0; i < C_DIM; ++i) {
            float ti = 0.f;
            #pragma unroll
            for (int j = 0; j < C_DIM; ++j) ti += sA[i * C_DIM + j] * s[j];
            bp[i] = ti * sB[i * M_DIM + xv];
            nu += bp[i];
        }
        ll += __logf(nu);
        float inv = 1.f / nu;
        #pragma unroll
        for (int i = 0; i < C_DIM; ++i) buf1[i * 128 + idx] = bp[i] * inv;
    }
    __syncthreads();

    // ---- L6..L0 (64..1 nodes): wave 0 only, LDS fences not barriers ----
    if (tid < 64) {
        float* cur = buf1; int cs = 128;
        float* nxt = buf0; int ns = 256;
        for (int cnt2 = 64; cnt2 >= 1; cnt2 >>= 1) {
            if (tid < cnt2) {
                const int idx = tid;
                float s[C_DIM];
                #pragma unroll
                for (int j = 0; j < C_DIM; ++j) {
                    float a  = cur[j * cs + 2 * idx];
                    float b2 = cur[j * cs + 2 * idx + 1];
                    s[j] = 0.5f * (a + b2);
                }
                const int xv = xs[cnt2 - 1 + idx];
                float bp[C_DIM]; float nu = 0.f;
                #pragma unroll
                for (int i = 0; i < C_DIM; ++i) {
                    float ti = 0.f;
                    #pragma unroll
                    for (int j = 0; j < C_DIM; ++j) ti += sA[i * C_DIM + j] * s[j];
                    bp[i] = ti * sB[i * M_DIM + xv];
                    nu += bp[i];
                }
                ll += __logf(nu);
                float inv = 1.f / nu;
                #pragma unroll
                for (int i = 0; i < C_DIM; ++i) nxt[i * ns + idx] = bp[i] * inv;
            }
            asm volatile("s_waitcnt lgkmcnt(0)" ::: "memory");
            __builtin_amdgcn_wave_barrier();
            float* tp = cur; cur = nxt; nxt = tp;
            int ts = cs; cs = ns; ns = ts;
        }
    }

    // ---- reduce ll across block ----
    float v = ll;
    #pragma unroll
    for (int off = 32; off > 0; off >>= 1) v += __shfl_down(v, off, 64);
    if ((tid & 63) == 0) wsum[tid >> 6] = v;
    __syncthreads();
    if (tid == 0) out[t * G_DIM + g] = wsum[0] + wsum[1] + wsum[2] + wsum[3];
}

extern "C" void kernel_launch(void* const* d_in, const int* in_sizes, int n_in,
                              void* d_out, int out_size, void* d_ws, size_t ws_size,
                              hipStream_t stream) {
    const int*   x       = (const int*)d_in[0];
    const int*   inv_map = (const int*)d_in[6];
    const float* lA      = (const float*)d_in[7];
    const float* lB      = (const float*)d_in[8];
    const float* lPi     = (const float*)d_in[9];
    float* out = (float*)d_out;

    htmm_fused<<<dim3(NBLOCKS), dim3(256), 0, stream>>>(
        x, inv_map, lA, lB, lPi, out);
}

// Round 5
// 166.781 us; speedup vs baseline: 1.7409x; 1.0210x over previous
//
#include <hip/hip_runtime.h>

// UniformBottomUpHTMM: T=64 trees, depth 10 (N1=2047 heap layout), C=16,
// M=64, G=16. r16: cap >= demand. The spill ledger across rounds:
//   cap  64 (no-bounds / (256,4)) -> ~1.1 KB/thread scratch writes
//   cap 128 ((256,2), unrolled)   -> ~360 B/thread
//   cap 128 ((256,2), rolled)     -> ~320 B/thread  (rolling barely helps)
// 320 B/thread * 256K threads = the observed 80 MB WRITE_SIZE exactly.
// Natural demand ~210 VGPR; every prior config capped below it.
// __launch_bounds__(256,1) raises the cap to 256 (NOT the same as no
// bounds, which assumes 1024-thread blocks -> cap 64). Expect VGPR~210,
// zero scratch, ~8 waves/CU -- fine, since with spill gone the kernel is
// pure VALU+LDS with high per-thread ILP. Full unroll restored (register
// pressure no longer needs artificial suppression).
// Structure: 1024 independent blocks, one (t,g) each, no workspace, no
// atomics, no device barrier.

#define C_DIM 16
#define M_DIM 64
#define G_DIM 16
#define T_TREES 64
#define N1 2047
#define NBLOCKS (T_TREES * G_DIM)   // 1024

__global__ __launch_bounds__(256, 1) void htmm_fused(
    const int* __restrict__ x,
    const int* __restrict__ inv_map,
    const float* __restrict__ lA,
    const float* __restrict__ lB,
    const float* __restrict__ lPi,
    float* __restrict__ out)
{
    const int bid = blockIdx.x;           // 1024 blocks: g = bid>>6, t = bid&63
    const int tid = threadIdx.x;
    const int g = bid >> 6;
    const int t = bid & (T_TREES - 1);    // all 16 same-tree blocks land on one XCD (64%8==0)

    __shared__ __align__(16) float sA[C_DIM * C_DIM];
    __shared__ __align__(16) float sB[C_DIM * M_DIM];
    __shared__ __align__(16) float sPi[C_DIM];
    __shared__ __align__(16) unsigned char xs[2048];
    __shared__ float buf0[C_DIM * 256];   // L8 betas (SoA stride 256)
    __shared__ float buf1[C_DIM * 128];
    __shared__ float wsum[4];

    // ---- per-block staging: tree symbols (coalesced; 16 blocks/tree hit L2) ----
    {
        const int base = t * N1;
        for (int i = tid; i < N1; i += 256)
            xs[i] = (unsigned char)x[inv_map[base + i]];
    }
    // ---- per-block param softmax for this g ----
    {   // A: softmax over i (axis 0) within 16-lane segments; one (i,j)/thread
        int j = tid >> 4, i = tid & 15;
        float v = lA[(i * C_DIM + j) * G_DIM + g];
        float mx = v;
        #pragma unroll
        for (int m = 1; m < 16; m <<= 1) mx = fmaxf(mx, __shfl_xor(mx, m, 16));
        float e = __expf(v - mx);
        float s = e;
        #pragma unroll
        for (int m = 1; m < 16; m <<= 1) s += __shfl_xor(s, m, 16);
        sA[i * C_DIM + j] = e / s;
    }
    {   // B: softmax over m (axis 1), row c, 4 symbols per lane
        int c = tid >> 4, l16 = tid & 15;
        float e0 = lB[(c * M_DIM + l16 +  0) * G_DIM + g];
        float e1 = lB[(c * M_DIM + l16 + 16) * G_DIM + g];
        float e2 = lB[(c * M_DIM + l16 + 32) * G_DIM + g];
        float e3 = lB[(c * M_DIM + l16 + 48) * G_DIM + g];
        float mx = fmaxf(fmaxf(e0, e1), fmaxf(e2, e3));
        #pragma unroll
        for (int m = 1; m < 16; m <<= 1) mx = fmaxf(mx, __shfl_xor(mx, m, 16));
        e0 = __expf(e0 - mx); e1 = __expf(e1 - mx);
        e2 = __expf(e2 - mx); e3 = __expf(e3 - mx);
        float s = e0 + e1 + e2 + e3;
        #pragma unroll
        for (int m = 1; m < 16; m <<= 1) s += __shfl_xor(s, m, 16);
        float inv = 1.f / s;
        sB[c * M_DIM + l16 +  0] = e0 * inv;
        sB[c * M_DIM + l16 + 16] = e1 * inv;
        sB[c * M_DIM + l16 + 32] = e2 * inv;
        sB[c * M_DIM + l16 + 48] = e3 * inv;
    }
    if (tid < C_DIM) {  // Pi: softmax over c across lanes 0..15
        float v = lPi[tid * G_DIM + g];
        float mx = v;
        #pragma unroll
        for (int m = 1; m < 16; m <<= 1) mx = fmaxf(mx, __shfl_xor(mx, m, 16));
        float e = __expf(v - mx);
        float s = e;
        #pragma unroll
        for (int m = 1; m < 16; m <<= 1) s += __shfl_xor(s, m, 16);
        sPi[tid] = e / s;
    }
    __syncthreads();

    float ll = 0.f;

    // ---- fused leaves (L10) + L9 + L8: one L8 node per thread ----
    {
        const int idx = tid;
        const int p8  = 255 + idx;
        float s8[C_DIM];
        #pragma unroll
        for (int k = 0; k < C_DIM; ++k) s8[k] = 0.f;
        #pragma unroll
        for (int c9 = 0; c9 < 2; ++c9) {
            const int p9 = 2 * p8 + 1 + c9;
            float s9[C_DIM];
            #pragma unroll
            for (int k = 0; k < C_DIM; ++k) s9[k] = 0.f;
            #pragma unroll
            for (int cl = 0; cl < 2; ++cl) {
                const int xv = xs[2 * p9 + 1 + cl];
                float b[C_DIM]; float nu = 0.f;
                #pragma unroll
                for (int k = 0; k < C_DIM; ++k) {
                    b[k] = sPi[k] * sB[k * M_DIM + xv];
                    nu += b[k];
                }
                float inv = 0.5f / nu;
                #pragma unroll
                for (int k = 0; k < C_DIM; ++k) s9[k] += b[k] * inv;
                ll += __logf(nu);
            }
            const int xv = xs[p9];
            float bp[C_DIM]; float nu = 0.f;
            #pragma unroll
            for (int i = 0; i < C_DIM; ++i) {
                float ti = 0.f;
                #pragma unroll
                for (int j = 0; j < C_DIM; ++j) ti += sA[i * C_DIM + j] * s9[j];
                bp[i] = ti * sB[i * M_DIM + xv];
                nu += bp[i];
            }
            ll += __logf(nu);
            float inv = 0.5f / nu;
            #pragma unroll
            for (int k = 0; k < C_DIM; ++k) s8[k] += bp[k] * inv;
        }
        const int xv = xs[p8];
        float bp[C_DIM]; float nu = 0.f;
        #pragma unroll
        for (int i = 0; i < C_DIM; ++i) {
            float ti = 0.f;
            #pragma unroll
            for (int j = 0; j < C_DIM; ++j) ti += sA[i * C_DIM + j] * s8[j];
            bp[i] = ti * sB[i * M_DIM + xv];
            nu += bp[i];
        }
        ll += __logf(nu);
        float inv = 1.f / nu;
        #pragma unroll
        for (int k = 0; k < C_DIM; ++k) buf0[k * 256 + idx] = bp[k] * inv;
    }
    __syncthreads();

    // ---- L7: 128 nodes ----
    if (tid < 128) {
        const int idx = tid;
        float s[C_DIM];
        #pragma unroll
        for (int j = 0; j < C_DIM; ++j) {
            float2 cv = ((const float2*)(buf0 + j * 256))[idx];
            s[j] = 0.5f * (cv.x + cv.y);
        }
        const int xv = xs[127 + idx];
        float bp[C_DIM]; float nu = 0.f;
        #pragma unroll
        for (int i = 0; i < C_DIM; ++i) {
            float ti = 0.f;
            #pragma unroll
            for (int j = 0; j < C_DIM; ++j) ti += sA[i * C_DIM + j] * s[j];
            bp[i] = ti * sB[i * M_DIM + xv];
            nu += bp[i];
        }
        ll += __logf(nu);
        float inv = 1.f / nu;
        #pragma unroll
        for (int i = 0; i < C_DIM; ++i) buf1[i * 128 + idx] = bp[i] * inv;
    }
    __syncthreads();

    // ---- L6..L0 (64..1 nodes): wave 0 only, LDS fences not barriers ----
    if (tid < 64) {
        float* cur = buf1; int cs = 128;
        float* nxt = buf0; int ns = 256;
        for (int cnt2 = 64; cnt2 >= 1; cnt2 >>= 1) {
            if (tid < cnt2) {
                const int idx = tid;
                float s[C_DIM];
                #pragma unroll
                for (int j = 0; j < C_DIM; ++j) {
                    float a  = cur[j * cs + 2 * idx];
                    float b2 = cur[j * cs + 2 * idx + 1];
                    s[j] = 0.5f * (a + b2);
                }
                const int xv = xs[cnt2 - 1 + idx];
                float bp[C_DIM]; float nu = 0.f;
                #pragma unroll
                for (int i = 0; i < C_DIM; ++i) {
                    float ti = 0.f;
                    #pragma unroll
                    for (int j = 0; j < C_DIM; ++j) ti += sA[i * C_DIM + j] * s[j];
                    bp[i] = ti * sB[i * M_DIM + xv];
                    nu += bp[i];
                }
                ll += __logf(nu);
                float inv = 1.f / nu;
                #pragma unroll
                for (int i = 0; i < C_DIM; ++i) nxt[i * ns + idx] = bp[i] * inv;
            }
            asm volatile("s_waitcnt lgkmcnt(0)" ::: "memory");
            __builtin_amdgcn_wave_barrier();
            float* tp = cur; cur = nxt; nxt = tp;
            int ts = cs; cs = ns; ns = ts;
        }
    }

    // ---- reduce ll across block ----
    float v = ll;
    #pragma unroll
    for (int off = 32; off > 0; off >>= 1) v += __shfl_down(v, off, 64);
    if ((tid & 63) == 0) wsum[tid >> 6] = v;
    __syncthreads();
    if (tid == 0) out[t * G_DIM + g] = wsum[0] + wsum[1] + wsum[2] + wsum[3];
}

extern "C" void kernel_launch(void* const* d_in, const int* in_sizes, int n_in,
                              void* d_out, int out_size, void* d_ws, size_t ws_size,
                              hipStream_t stream) {
    const int*   x       = (const int*)d_in[0];
    const int*   inv_map = (const int*)d_in[6];
    const float* lA      = (const float*)d_in[7];
    const float* lB      = (const float*)d_in[8];
    const float* lPi     = (const float*)d_in[9];
    float* out = (float*)d_out;

    htmm_fused<<<dim3(NBLOCKS), dim3(256), 0, stream>>>(
        x, inv_map, lA, lB, lPi, out);
}

// Round 6
// 147.170 us; speedup vs baseline: 1.9729x; 1.1333x over previous
//
#include <hip/hip_runtime.h>

// UniformBottomUpHTMM: T=64 trees, depth 10 (N1=2047 heap), C=16, M=64,
// G=16. r17: attack the LDS issue pipe. r16 proved spill-free (WRITE 4KB,
// VGPR 160) yet ran 103us at VALUBusy 17% -- latency/issue-bound on LDS:
// each 16x16 matvec read 256 sA values as scalar broadcast ds_read_b32
// (~770/thread in leaf phase) + 64 scalar sB gathers per thread; ~900 LDS
// instr/wave x 16 waves/CU serialized on the one LDS pipe ~= the 103us.
// Changes:
//  1. Leaf betas depend ONLY on xv (64 symbols): per-block tables
//     PB[xv][k] = 0.5*Pi[k]*B[k][xv]/nu(xv) and logNu[xv]. Leaves become
//     4x ds_read_b128 + log LOOKUP (kills 64 gathers + half the __logf).
//  2. A-reads vectorized: 64x uniform ds_read_b128/matvec (was 256 b32).
//  3. B transposed to Bt[xv][i], stride 20 floats (bank spread): 4x b128
//     per internal node (was 16 scalar gathers).
//  4. __launch_bounds__(256,1): proven cap>=demand zero-spill config;
//     occupancy follows ACTUAL VGPR, so lower demand = more waves free.
// Structure: 1024 independent blocks, one (t,g) each, no workspace/atomics.

#define C_DIM 16
#define M_DIM 64
#define G_DIM 16
#define T_TREES 64
#define N1 2047
#define NBLOCKS (T_TREES * G_DIM)   // 1024
#define BTS 20                      // padded row stride (floats) for xv-tables

__device__ __forceinline__ float4 f4add(float4 a, float4 b) {
    return make_float4(a.x + b.x, a.y + b.y, a.z + b.z, a.w + b.w);
}
__device__ __forceinline__ float4 f4mul(float4 a, float4 b) {
    return make_float4(a.x * b.x, a.y * b.y, a.z * b.z, a.w * b.w);
}
__device__ __forceinline__ float4 f4fma(float4 a, float4 b, float4 c) {
    return make_float4(fmaf(a.x, b.x, c.x), fmaf(a.y, b.y, c.y),
                       fmaf(a.z, b.z, c.z), fmaf(a.w, b.w, c.w));
}
__device__ __forceinline__ float hsum4(float4 a) { return a.x + a.y + a.z + a.w; }

// ti[i] = sum_j A[i][j]*s[j]; bp[q] = ti4*Bt4; returns nu = sum_i bp[i]
__device__ __forceinline__ float matvec_bt(const float* __restrict__ A,
                                           const float* __restrict__ bt,
                                           const float4 sv[4], float4 bp[4])
{
    float tarr[16];
    #pragma unroll
    for (int i = 0; i < 16; ++i) {
        const float4* ar = (const float4*)(A + i * 16);
        float4 m = f4mul(ar[0], sv[0]);
        m = f4fma(ar[1], sv[1], m);
        m = f4fma(ar[2], sv[2], m);
        m = f4fma(ar[3], sv[3], m);
        tarr[i] = hsum4(m);
    }
    float nu = 0.f;
    #pragma unroll
    for (int q = 0; q < 4; ++q) {
        float4 b4 = *(const float4*)(bt + 4 * q);
        float4 t4 = make_float4(tarr[4*q], tarr[4*q+1], tarr[4*q+2], tarr[4*q+3]);
        bp[q] = f4mul(t4, b4);
        nu += hsum4(bp[q]);
    }
    return nu;
}

__global__ __launch_bounds__(256, 1) void htmm_fused(
    const int* __restrict__ x,
    const int* __restrict__ inv_map,
    const float* __restrict__ lA,
    const float* __restrict__ lB,
    const float* __restrict__ lPi,
    float* __restrict__ out)
{
    const int bid = blockIdx.x;           // 1024 blocks: g = bid>>6, t = bid&63
    const int tid = threadIdx.x;
    const int g = bid >> 6;
    const int t = bid & (T_TREES - 1);

    __shared__ __align__(16) float sA[C_DIM * C_DIM];
    __shared__ __align__(16) float sBt[M_DIM * BTS];   // Bt[xv][c], stride 20
    __shared__ __align__(16) float sPB[M_DIM * BTS];   // 0.5*Pi*B/nu per xv
    __shared__ float sLog[M_DIM];                      // log(nu_leaf(xv))
    __shared__ float sPi[C_DIM];
    __shared__ __align__(16) unsigned char xs[2048];
    __shared__ float buf0[C_DIM * 256];   // L8 betas (SoA stride 256)
    __shared__ float buf1[C_DIM * 128];
    __shared__ float wsum[4];

    // ---- tree symbols (coalesced; 16 same-tree blocks share L2) ----
    {
        const int base = t * N1;
        for (int i = tid; i < N1; i += 256)
            xs[i] = (unsigned char)x[inv_map[base + i]];
    }
    // ---- A softmax (over i within 16-lane segments) ----
    {
        int j = tid >> 4, i = tid & 15;
        float v = lA[(i * C_DIM + j) * G_DIM + g];
        float mx = v;
        #pragma unroll
        for (int m = 1; m < 16; m <<= 1) mx = fmaxf(mx, __shfl_xor(mx, m, 16));
        float e = __expf(v - mx);
        float s = e;
        #pragma unroll
        for (int m = 1; m < 16; m <<= 1) s += __shfl_xor(s, m, 16);
        sA[i * C_DIM + j] = e / s;
    }
    // ---- B softmax (over m), written TRANSPOSED: sBt[xv*BTS + c] ----
    {
        int c = tid >> 4, l16 = tid & 15;
        float e0 = lB[(c * M_DIM + l16 +  0) * G_DIM + g];
        float e1 = lB[(c * M_DIM + l16 + 16) * G_DIM + g];
        float e2 = lB[(c * M_DIM + l16 + 32) * G_DIM + g];
        float e3 = lB[(c * M_DIM + l16 + 48) * G_DIM + g];
        float mx = fmaxf(fmaxf(e0, e1), fmaxf(e2, e3));
        #pragma unroll
        for (int m = 1; m < 16; m <<= 1) mx = fmaxf(mx, __shfl_xor(mx, m, 16));
        e0 = __expf(e0 - mx); e1 = __expf(e1 - mx);
        e2 = __expf(e2 - mx); e3 = __expf(e3 - mx);
        float s = e0 + e1 + e2 + e3;
        #pragma unroll
        for (int m = 1; m < 16; m <<= 1) s += __shfl_xor(s, m, 16);
        float inv = 1.f / s;
        sBt[(l16 +  0) * BTS + c] = e0 * inv;
        sBt[(l16 + 16) * BTS + c] = e1 * inv;
        sBt[(l16 + 32) * BTS + c] = e2 * inv;
        sBt[(l16 + 48) * BTS + c] = e3 * inv;
    }
    if (tid < C_DIM) {  // Pi softmax
        float v = lPi[tid * G_DIM + g];
        float mx = v;
        #pragma unroll
        for (int m = 1; m < 16; m <<= 1) mx = fmaxf(mx, __shfl_xor(mx, m, 16));
        float e = __expf(v - mx);
        float s = e;
        #pragma unroll
        for (int m = 1; m < 16; m <<= 1) s += __shfl_xor(s, m, 16);
        sPi[tid] = e / s;
    }
    __syncthreads();

    // ---- leaf tables: PB[xv][k] = 0.5*Pi[k]*Bt[xv][k]/nu, logNu[xv] ----
    if (tid < M_DIM) {
        const int xv = tid;
        float pb[16]; float nu = 0.f;
        #pragma unroll
        for (int k = 0; k < 16; ++k) {
            pb[k] = sPi[k] * sBt[xv * BTS + k];
            nu += pb[k];
        }
        const float inv = 0.5f / nu;
        #pragma unroll
        for (int k = 0; k < 16; ++k) sPB[xv * BTS + k] = pb[k] * inv;
        sLog[xv] = __logf(nu);
    }
    __syncthreads();

    float ll = 0.f;

    // ---- fused leaves (table) + L9 + L8: one L8 node per thread ----
    {
        const int idx = tid;
        const int p8  = 255 + idx;
        float4 s8v[4];
        #pragma unroll
        for (int q = 0; q < 4; ++q) s8v[q] = make_float4(0.f, 0.f, 0.f, 0.f);

        #pragma unroll
        for (int c9 = 0; c9 < 2; ++c9) {
            const int p9 = 2 * p8 + 1 + c9;
            const int xl = xs[2 * p9 + 1], xr = xs[2 * p9 + 2];
            const float* pl = &sPB[xl * BTS];
            const float* pr = &sPB[xr * BTS];
            float4 s9v[4];
            #pragma unroll
            for (int q = 0; q < 4; ++q)
                s9v[q] = f4add(*(const float4*)(pl + 4*q), *(const float4*)(pr + 4*q));
            ll += sLog[xl] + sLog[xr];

            const int xv = xs[p9];
            float4 bp[4];
            float nu = matvec_bt(sA, &sBt[xv * BTS], s9v, bp);
            ll += __logf(nu);
            const float inv = 0.5f / nu;
            const float4 iv = make_float4(inv, inv, inv, inv);
            #pragma unroll
            for (int q = 0; q < 4; ++q) s8v[q] = f4fma(bp[q], iv, s8v[q]);
        }
        const int xv = xs[p8];
        float4 bp[4];
        float nu = matvec_bt(sA, &sBt[xv * BTS], s8v, bp);
        ll += __logf(nu);
        const float inv = 1.f / nu;
        #pragma unroll
        for (int q = 0; q < 4; ++q) {
            buf0[(4*q + 0) * 256 + idx] = bp[q].x * inv;
            buf0[(4*q + 1) * 256 + idx] = bp[q].y * inv;
            buf0[(4*q + 2) * 256 + idx] = bp[q].z * inv;
            buf0[(4*q + 3) * 256 + idx] = bp[q].w * inv;
        }
    }
    __syncthreads();

    // ---- L7: 128 nodes ----
    if (tid < 128) {
        const int idx = tid;
        float sarr[16];
        #pragma unroll
        for (int j = 0; j < 16; ++j) {
            float2 cv = *(const float2*)(&buf0[j * 256 + 2 * idx]);
            sarr[j] = 0.5f * (cv.x + cv.y);
        }
        float4 sv[4];
        #pragma unroll
        for (int q = 0; q < 4; ++q)
            sv[q] = make_float4(sarr[4*q], sarr[4*q+1], sarr[4*q+2], sarr[4*q+3]);
        const int xv = xs[127 + idx];
        float4 bp[4];
        float nu = matvec_bt(sA, &sBt[xv * BTS], sv, bp);
        ll += __logf(nu);
        const float inv = 1.f / nu;
        #pragma unroll
        for (int q = 0; q < 4; ++q) {
            buf1[(4*q + 0) * 128 + idx] = bp[q].x * inv;
            buf1[(4*q + 1) * 128 + idx] = bp[q].y * inv;
            buf1[(4*q + 2) * 128 + idx] = bp[q].z * inv;
            buf1[(4*q + 3) * 128 + idx] = bp[q].w * inv;
        }
    }
    __syncthreads();

    // ---- L6..L0 (64..1 nodes): wave 0 only, LDS fences not barriers ----
    if (tid < 64) {
        float* cur = buf1; int cs = 128;
        float* nxt = buf0; int ns = 256;
        for (int cnt2 = 64; cnt2 >= 1; cnt2 >>= 1) {
            if (tid < cnt2) {
                const int idx = tid;
                float sarr[16];
                #pragma unroll
                for (int j = 0; j < 16; ++j) {
                    float2 cv = *(const float2*)(&cur[j * cs + 2 * idx]);
                    sarr[j] = 0.5f * (cv.x + cv.y);
                }
                float4 sv[4];
                #pragma unroll
                for (int q = 0; q < 4; ++q)
                    sv[q] = make_float4(sarr[4*q], sarr[4*q+1], sarr[4*q+2], sarr[4*q+3]);
                const int xv = xs[cnt2 - 1 + idx];
                float4 bp[4];
                float nu = matvec_bt(sA, &sBt[xv * BTS], sv, bp);
                ll += __logf(nu);
                const float inv = 1.f / nu;
                #pragma unroll
                for (int q = 0; q < 4; ++q) {
                    nxt[(4*q + 0) * ns + idx] = bp[q].x * inv;
                    nxt[(4*q + 1) * ns + idx] = bp[q].y * inv;
                    nxt[(4*q + 2) * ns + idx] = bp[q].z * inv;
                    nxt[(4*q + 3) * ns + idx] = bp[q].w * inv;
                }
            }
            asm volatile("s_waitcnt lgkmcnt(0)" ::: "memory");
            __builtin_amdgcn_wave_barrier();
            float* tp = cur; cur = nxt; nxt = tp;
            int ts = cs; cs = ns; ns = ts;
        }
    }

    // ---- reduce ll across block ----
    float v = ll;
    #pragma unroll
    for (int off = 32; off > 0; off >>= 1) v += __shfl_down(v, off, 64);
    if ((tid & 63) == 0) wsum[tid >> 6] = v;
    __syncthreads();
    if (tid == 0) out[t * G_DIM + g] = wsum[0] + wsum[1] + wsum[2] + wsum[3];
}

extern "C" void kernel_launch(void* const* d_in, const int* in_sizes, int n_in,
                              void* d_out, int out_size, void* d_ws, size_t ws_size,
                              hipStream_t stream) {
    const int*   x       = (const int*)d_in[0];
    const int*   inv_map = (const int*)d_in[6];
    const float* lA      = (const float*)d_in[7];
    const float* lB      = (const float*)d_in[8];
    const float* lPi     = (const float*)d_in[9];
    float* out = (float*)d_out;

    htmm_fused<<<dim3(NBLOCKS), dim3(256), 0, stream>>>(
        x, inv_map, lA, lB, lPi, out);
}